// Round 6
// baseline (202.959 us; speedup 1.0000x reference)
//
#include <hip/hip_runtime.h>

// Problem constants
#define BN 32768
#define KN 5
#define LN 128
#define HN 3
#define ROWS (BN*KN)        // 163840
#define BK ROWS
#define MT 160              // rows per tile (aligned: 32 b-groups of 5 anchors)
#define TILES (ROWS/MT)     // 1024
#define WGS 256             // one WG per CU, single round
#define TPW (TILES/WGS)     // 4 tiles per workgroup
#define THREADS 512         // 8 waves
#define ASTR 168            // A row stride bf16: [emb16|h128|zero16] + 8 pad
#define NMT (MT/16)         // 10 m-tiles per step
#define LOG2E 1.44269504089f

using bf16x8 = __attribute__((ext_vector_type(8))) __bf16;
using bf16x2 = __attribute__((ext_vector_type(2))) __bf16;
using f32x4  = __attribute__((ext_vector_type(4))) float;
using u16x8  = __attribute__((ext_vector_type(8))) unsigned short;

__device__ inline unsigned short f2bf(float x) {
    union { float f; unsigned u; } v; v.f = x;
    unsigned r = v.u + 0x7FFFu + ((v.u >> 16) & 1u);   // RNE
    return (unsigned short)(r >> 16);
}
#if __has_builtin(__builtin_amdgcn_cvt_pk_bf16_f32)
__device__ inline unsigned short f2bf_fast(float x) {
    union { bf16x2 v; unsigned short us[2]; } u;
    u.v = __builtin_amdgcn_cvt_pk_bf16_f32(x, x);
    return u.us[0];
}
__device__ inline unsigned pk2bf(float lo, float hi) {   // D.lo=bf16(S0), D.hi=bf16(S1)
    union { bf16x2 v; unsigned u; } q;
    q.v = __builtin_amdgcn_cvt_pk_bf16_f32(lo, hi);
    return q.u;
}
#else
__device__ inline unsigned short f2bf_fast(float x) { return f2bf(x); }
__device__ inline unsigned pk2bf(float lo, float hi) {
    return (unsigned)f2bf(lo) | ((unsigned)f2bf(hi) << 16);
}
#endif
__device__ inline float bf2f(unsigned short b) {
    union { unsigned u; float f; } v; v.u = ((unsigned)b) << 16; return v.f;
}
__device__ inline float sigm(float x) {
    return __builtin_amdgcn_rcpf(1.0f + __builtin_amdgcn_exp2f(-LOG2E * x));
}
__device__ inline f32x4 splat4(float x) { f32x4 r; r[0]=x; r[1]=x; r[2]=x; r[3]=x; return r; }

// Pointwise LSTM nonlinearity for one m-tile (4 acc rows), acc bank ACCI,
// logical m-tile MTI (0..9). WB_ = per-thread write base into next h buffer.
#define PW_MT(ACCI, MTI, WB_) do {                                                 \
    _Pragma("unroll")                                                              \
    for (int r_ = 0; r_ < 4; ++r_) {                                               \
        const float Ei = __builtin_amdgcn_exp2f(acc[ACCI][0][r_]);  /* e^-i  */    \
        const float Ef = __builtin_amdgcn_exp2f(acc[ACCI][1][r_]);  /* e^-f  */    \
        const float Eg = __builtin_amdgcn_exp2f(acc[ACCI][2][r_]);  /* e^{2g}*/    \
        const float Eo = __builtin_amdgcn_exp2f(acc[ACCI][3][r_]);  /* e^-o  */    \
        const float t1  = (1.0f + Ei) * (1.0f + Eg);                               \
        const float ef1 = 1.0f + Ef;                                               \
        const float t3  = (Eg - 1.0f) * ef1;                                       \
        const float num = fmaf(cst[(MTI)*4 + r_], t1, t3);                         \
        const float cn  = num * __builtin_amdgcn_rcpf(t1 * ef1);                   \
        cst[(MTI)*4 + r_] = cn;                                                    \
        const float Ec = __builtin_amdgcn_exp2f(2.0f * LOG2E * cn);                \
        const float hn = (Ec - 1.0f) *                                             \
            __builtin_amdgcn_rcpf((1.0f + Eo) * (1.0f + Ec));                      \
        (WB_)[(MTI)*16*ASTR + r_*ASTR] = f2bf_fast(hn);                            \
    }                                                                              \
} while (0)

__global__ __launch_bounds__(THREADS, 2)   // 256-reg cap
void wahead_kernel(const float* __restrict__ z,   const float* __restrict__ anchors,
                   const float* __restrict__ W1,  const float* __restrict__ b1,
                   const float* __restrict__ W2,  const float* __restrict__ b2,
                   const float* __restrict__ Wih, const float* __restrict__ Whh,
                   const float* __restrict__ bih, const float* __restrict__ bhh,
                   const float* __restrict__ Wp,  const float* __restrict__ bp,
                   const float* __restrict__ Wr,  const float* __restrict__ br,
                   float* __restrict__ out)
{
    __shared__ unsigned short sA[2 * MT * ASTR];   // ping-pong [emb|h|0] bf16, 105 KB
    __shared__ float sW1[32], sb1[16], sW2[16 * 17], sb2[16], sWp[128], sWr[384];

    const int tid  = threadIdx.x;
    const int wv   = tid >> 6;       // wave 0..7: owns l-cols wv*16..wv*16+15 of each gate
    const int lane = tid & 63;
    const int quad = lane >> 4;
    const int cc   = lane & 15;
    const int lcol = wv * 16 + cc;

    // ---- stage small constant weights into LDS ----
    if (tid < 32)  sW1[tid] = W1[tid];
    if (tid < 16)  { sb1[tid] = b1[tid]; sb2[tid] = b2[tid]; }
    if (tid < 256) sW2[(tid >> 4) * 17 + (tid & 15)] = W2[tid];   // sW2[col*17+hh]
    if (tid < 128) sWp[tid] = Wp[tid];
    if (tid < 384) sWr[tid] = Wr[tid];

    // ---- zero-pad cols (144..159) of ALL rows, both buffers, ONCE ----
    // 2 bufs x 160 rows x 16 cols = 5120 ush = 10 u32/thread
    {
        #pragma unroll
        for (int c = 0; c < 3; ++c) {
            const int idx = c * 512 + tid;           // 0..1535 of 1280 slots (guard)
            if (idx < 2 * MT * 8) {
                const int bufr = idx >> 3;           // buf*MT + row
                const int cp   = idx & 7;            // u32 pair within pad
                *reinterpret_cast<unsigned*>(&sA[bufr * ASTR + 144 + cp * 2]) = 0u;
            }
        }
    }

    // ---- stacked-B fragments [W_ih(16)|W_hh(128)|0(16)] with FOLDED gate scales ----
    // gates i,f,o scaled by -log2e; gate g scaled by +2*log2e, so exp2() applies
    // directly to the MFMA accumulators.  B layout (16x16x32): n=lane&15, k=quad*8+j
    bf16x8 Bf[4][5];
    float  biasv[4];
    #pragma unroll
    for (int t = 0; t < 4; ++t) {                      // gate i,f,g,o
        const float sc = (t == 2) ? (2.0f * LOG2E) : (-LOG2E);
        const int n = t * 128 + wv * 16 + cc;          // gate output col in [0,512)
        biasv[t] = sc * (bih[n] + bhh[n]);
        #pragma unroll
        for (int kt = 0; kt < 5; ++kt) {
            const int k0 = kt * 32 + quad * 8;
            float v[8];
            if (k0 < 16) {                             // W_ih region
                const float4 p0 = *reinterpret_cast<const float4*>(Wih + n * 16 + k0);
                const float4 p1 = *reinterpret_cast<const float4*>(Wih + n * 16 + k0 + 4);
                v[0]=p0.x; v[1]=p0.y; v[2]=p0.z; v[3]=p0.w;
                v[4]=p1.x; v[5]=p1.y; v[6]=p1.z; v[7]=p1.w;
            } else if (k0 < 144) {                     // W_hh region
                const float4 p0 = *reinterpret_cast<const float4*>(Whh + n * 128 + (k0 - 16));
                const float4 p1 = *reinterpret_cast<const float4*>(Whh + n * 128 + (k0 - 16) + 4);
                v[0]=p0.x; v[1]=p0.y; v[2]=p0.z; v[3]=p0.w;
                v[4]=p1.x; v[5]=p1.y; v[6]=p1.z; v[7]=p1.w;
            } else {                                   // zero pad k in [144,160)
                #pragma unroll
                for (int j = 0; j < 8; ++j) v[j] = 0.0f;
            }
            union { bf16x8 bv; unsigned short us[8]; } pk;
            #pragma unroll
            for (int j = 0; j < 8; ++j) pk.us[j] = f2bf(sc * v[j]);
            Bf[t][kt] = pk.bv;
        }
    }

    const float bpv = bp[0];
    const float br0 = br[0], br1 = br[1], br2 = br[2];

    __syncthreads();   // consts + pad staged

    const int erow = tid >> 2;   // 0..127 (4 threads per row)
    const int esub = tid & 3;    // 0..3

    // ---- per-thread LDS base pointers (per buffer): step addressing is
    //      base + compile-time immediate ----
    const unsigned short* rbB[2];   // A-frag read base: row cc, k-offset quad*8
    unsigned short*       wbB[2];   // h write base: row quad*4, col 16+lcol
    rbB[0] = &sA[0 * MT * ASTR + cc * ASTR + quad * 8];
    rbB[1] = &sA[1 * MT * ASTR + cc * ASTR + quad * 8];
    wbB[0] = &sA[0 * MT * ASTR + (quad * 4) * ASTR + 16 + lcol];
    wbB[1] = &sA[1 * MT * ASTR + (quad * 4) * ASTR + 16 + lcol];

    #pragma unroll 1
    for (int ti = 0; ti < TPW; ++ti) {
        const int tile = blockIdx.x * TPW + ti;
        const int r0g  = tile * MT;

        // -------- staging: emb MLP (4 cols/thread) + initial h = z --------
        // two passes: rows 0..127 (all threads), rows 128..159 (tid<128)
        #pragma unroll 1
        for (int rr = erow; rr < MT; rr += 128) {
            const int gr = r0g + rr;
            const float2 an = *reinterpret_cast<const float2*>(anchors + gr * 2);
            const int e0 = esub * 4;
            float a0 = sb2[e0], a1 = sb2[e0 + 1], a2 = sb2[e0 + 2], a3 = sb2[e0 + 3];
            #pragma unroll
            for (int hh = 0; hh < 16; ++hh) {
                float pre = fmaf(sW1[hh * 2], an.x, fmaf(sW1[hh * 2 + 1], an.y, sb1[hh]));
                pre = fmaxf(pre, 0.0f);
                a0 = fmaf(pre, sW2[e0 * 17 + hh], a0);
                a1 = fmaf(pre, sW2[(e0 + 1) * 17 + hh], a1);
                a2 = fmaf(pre, sW2[(e0 + 2) * 17 + hh], a2);
                a3 = fmaf(pre, sW2[(e0 + 3) * 17 + hh], a3);
            }
            const unsigned ep0 = pk2bf(a0, a1), ep1 = pk2bf(a2, a3);
            #pragma unroll
            for (int bufi = 0; bufi < 2; ++bufi) {
                unsigned short* row = &sA[bufi * MT * ASTR + rr * ASTR];
                *reinterpret_cast<unsigned*>(&row[e0])     = ep0;
                *reinterpret_cast<unsigned*>(&row[e0 + 2]) = ep1;
            }
            // initial h = z[b] (bf16) into buffer 0, cols 16..143: 32 elems/thread
            const unsigned b_idx = (unsigned)gr / 5u;
            const float* zb = z + (size_t)b_idx * 128 + esub * 32;
            unsigned short* hrow = &sA[rr * ASTR + 16 + esub * 32];
            #pragma unroll
            for (int c = 0; c < 2; ++c) {
                const float4 q0 = *reinterpret_cast<const float4*>(zb + c * 16);
                const float4 q1 = *reinterpret_cast<const float4*>(zb + c * 16 + 4);
                const float4 q2 = *reinterpret_cast<const float4*>(zb + c * 16 + 8);
                const float4 q3 = *reinterpret_cast<const float4*>(zb + c * 16 + 12);
                union { u16x8 v; unsigned u32[4]; } w0, w1;
                w0.u32[0] = pk2bf(q0.x, q0.y); w0.u32[1] = pk2bf(q0.z, q0.w);
                w0.u32[2] = pk2bf(q1.x, q1.y); w0.u32[3] = pk2bf(q1.z, q1.w);
                w1.u32[0] = pk2bf(q2.x, q2.y); w1.u32[1] = pk2bf(q2.z, q2.w);
                w1.u32[2] = pk2bf(q3.x, q3.y); w1.u32[3] = pk2bf(q3.z, q3.w);
                *reinterpret_cast<u16x8*>(hrow + c * 16)     = w0.v;
                *reinterpret_cast<u16x8*>(hrow + c * 16 + 8) = w1.v;
            }
        }

        float cst[4 * NMT];
        #pragma unroll
        for (int e = 0; e < 4 * NMT; ++e) cst[e] = 0.0f;

        #pragma unroll
        for (int s = 0; s < HN; ++s) {
            const int cur = s & 1;          // compile-time after unroll
            const int nxt = cur ^ 1;
            __syncthreads();   // staging / previous-step h writes visible

            const unsigned short* rb = rbB[cur];
            unsigned short*       wb = wbB[nxt];

            // ---- 10 m-tiles: MFMA(mt) with af ping-pong prefetch; PW(mt-1)
            //      issued in MFMA(mt)'s window via acc bank ping-pong ----
            f32x4 acc[2][4];
            bf16x8 af[2][5];
            #pragma unroll
            for (int kt = 0; kt < 5; ++kt)
                af[0][kt] = *reinterpret_cast<const bf16x8*>(rb + kt * 32);

            #pragma unroll
            for (int mt = 0; mt < NMT; ++mt) {
                const int pb = mt & 1;
                #pragma unroll
                for (int t = 0; t < 4; ++t)
                    acc[pb][t] = splat4(biasv[t]);
                if (mt < NMT - 1) {
                    #pragma unroll
                    for (int kt = 0; kt < 5; ++kt)
                        af[pb ^ 1][kt] = *reinterpret_cast<const bf16x8*>(
                            rb + (mt + 1) * 16 * ASTR + kt * 32);
                }
                #pragma unroll
                for (int kt = 0; kt < 5; ++kt)
                    #pragma unroll
                    for (int t = 0; t < 4; ++t)
                        acc[pb][t] = __builtin_amdgcn_mfma_f32_16x16x32_bf16(
                            af[pb][kt], Bf[t][kt], acc[pb][t], 0, 0, 0);
                // pointwise of previous m-tile (independent of this mt's MFMAs)
                if      (mt == 1) PW_MT(0, 0, wb);
                else if (mt == 2) PW_MT(1, 1, wb);
                else if (mt == 3) PW_MT(0, 2, wb);
                else if (mt == 4) PW_MT(1, 3, wb);
                else if (mt == 5) PW_MT(0, 4, wb);
                else if (mt == 6) PW_MT(1, 5, wb);
                else if (mt == 7) PW_MT(0, 6, wb);
                else if (mt == 8) PW_MT(1, 7, wb);
                else if (mt == 9) PW_MT(0, 8, wb);
            }
            PW_MT(1, 9, wb);
        }

        __syncthreads();   // final h (buffer 1) complete

        // -------- epilogue: heads; 4 threads/row, 32 l each; two passes --------
        #pragma unroll 1
        for (int rr = erow; rr < MT; rr += 128) {
            const int j = esub;          // 0..3
            const unsigned short* hrow = &sA[1 * MT * ASTR + rr * ASTR + 16 + j * 32];
            float p = 0.f, q0 = 0.f, q1 = 0.f, q2 = 0.f;
            #pragma unroll
            for (int c = 0; c < 4; ++c) {
                const u16x8 hv8 = *reinterpret_cast<const u16x8*>(hrow + c * 8);
                #pragma unroll
                for (int u = 0; u < 8; ++u) {
                    const int l = j * 32 + c * 8 + u;
                    const float hv = bf2f(hv8[u]);
                    p  = fmaf(hv, sWp[l], p);
                    q0 = fmaf(hv, sWr[l], q0);
                    q1 = fmaf(hv, sWr[128 + l], q1);
                    q2 = fmaf(hv, sWr[256 + l], q2);
                }
            }
            #pragma unroll
            for (int m = 1; m < 4; m <<= 1) {
                p  += __shfl_xor(p,  m, 64);
                q0 += __shfl_xor(q0, m, 64);
                q1 += __shfl_xor(q1, m, 64);
                q2 += __shfl_xor(q2, m, 64);
            }
            if (j == 0) {
                const int gr = r0g + rr;
                const float prog  = p + bpv;
                const float rr0 = q0 + br0, rr1 = q1 + br1, rr2 = q2 + br2;
                const float rmean = (rr0 + rr1 + rr2) * (1.0f / 3.0f);
                const float s0 = sigm(rr0), s1 = sigm(rr1), s2 = sigm(rr2);
                const float sm = (s0 + s1 + s2) * (1.0f / 3.0f);
                const float d0 = s0 - sm, d1 = s1 - sm, d2 = s2 - sm;
                const float unc = (d0 * d0 + d1 * d1 + d2 * d2) * 0.5f;   // ddof=1
                out[gr]          = rmean;
                out[BK + gr]     = prog;
                out[2 * BK + gr] = unc;
                out[3 * BK + gr] = rr0;
                out[4 * BK + gr] = rr1;
                out[5 * BK + gr] = rr2;
            }
        }
        // next-tile staging writes emb cols (both bufs) + buf0 h (z);
        // epilogue reads buf1 h-cols — disjoint; step-0 barrier orders the rest.
    }
}

extern "C" void kernel_launch(void* const* d_in, const int* in_sizes, int n_in,
                              void* d_out, int out_size, void* d_ws, size_t ws_size,
                              hipStream_t stream) {
    const float* z       = (const float*)d_in[0];
    const float* anchors = (const float*)d_in[1];
    const float* W1      = (const float*)d_in[2];
    const float* b1      = (const float*)d_in[3];
    const float* W2      = (const float*)d_in[4];
    const float* b2      = (const float*)d_in[5];
    const float* Wih     = (const float*)d_in[6];
    const float* Whh     = (const float*)d_in[7];
    const float* bih     = (const float*)d_in[8];
    const float* bhh     = (const float*)d_in[9];
    const float* Wp      = (const float*)d_in[10];
    const float* bp      = (const float*)d_in[11];
    const float* Wr      = (const float*)d_in[12];
    const float* br      = (const float*)d_in[13];

    hipLaunchKernelGGL(wahead_kernel, dim3(WGS), dim3(THREADS), 0, stream,
                       z, anchors, W1, b1, W2, b2, Wih, Whh, bih, bhh,
                       Wp, bp, Wr, br, (float*)d_out);
}

// Round 8
// 202.519 us; speedup vs baseline: 1.0022x; 1.0022x over previous
//
#include <hip/hip_runtime.h>

// Problem constants
#define BN 32768
#define KN 5
#define LN 128
#define HN 3
#define ROWS (BN*KN)        // 163840
#define BK ROWS
#define MT 160              // rows per tile (aligned: 32 b-groups of 5 anchors)
#define TILES (ROWS/MT)     // 1024
#define WGS 256             // one WG per CU, single round
#define TPW (TILES/WGS)     // 4 tiles per workgroup
#define THREADS 512         // 8 waves
#define ASTR 168            // A row stride bf16: [emb16|h128|zero16] + 8 pad
#define NMT (MT/16)         // 10 m-tiles per step
#define LOG2E 1.44269504089f

using bf16x8 = __attribute__((ext_vector_type(8))) __bf16;
using bf16x2 = __attribute__((ext_vector_type(2))) __bf16;
using f32x4  = __attribute__((ext_vector_type(4))) float;
using u16x8  = __attribute__((ext_vector_type(8))) unsigned short;

__device__ inline unsigned short f2bf(float x) {
    union { float f; unsigned u; } v; v.f = x;
    unsigned r = v.u + 0x7FFFu + ((v.u >> 16) & 1u);   // RNE
    return (unsigned short)(r >> 16);
}
#if __has_builtin(__builtin_amdgcn_cvt_pk_bf16_f32)
__device__ inline unsigned short f2bf_fast(float x) {
    union { bf16x2 v; unsigned short us[2]; } u;
    u.v = __builtin_amdgcn_cvt_pk_bf16_f32(x, x);
    return u.us[0];
}
__device__ inline unsigned pk2bf(float lo, float hi) {   // D.lo=bf16(S0), D.hi=bf16(S1)
    union { bf16x2 v; unsigned u; } q;
    q.v = __builtin_amdgcn_cvt_pk_bf16_f32(lo, hi);
    return q.u;
}
#else
__device__ inline unsigned short f2bf_fast(float x) { return f2bf(x); }
__device__ inline unsigned pk2bf(float lo, float hi) {
    return (unsigned)f2bf(lo) | ((unsigned)f2bf(hi) << 16);
}
#endif
__device__ inline float bf2f(unsigned short b) {
    union { unsigned u; float f; } v; v.u = ((unsigned)b) << 16; return v.f;
}
__device__ inline float sigm(float x) {
    return __builtin_amdgcn_rcpf(1.0f + __builtin_amdgcn_exp2f(-LOG2E * x));
}
__device__ inline f32x4 splat4(float x) { f32x4 r; r[0]=x; r[1]=x; r[2]=x; r[3]=x; return r; }

// Pointwise LSTM nonlinearity for one m-tile (4 acc rows), acc bank ACCI,
// logical m-tile MTI (0..9). WB_ = per-thread write base into next h buffer.
#define PW_MT(ACCI, MTI, WB_) do {                                                 \
    _Pragma("unroll")                                                              \
    for (int r_ = 0; r_ < 4; ++r_) {                                               \
        const float Ei = __builtin_amdgcn_exp2f(acc[ACCI][0][r_]);  /* e^-i  */    \
        const float Ef = __builtin_amdgcn_exp2f(acc[ACCI][1][r_]);  /* e^-f  */    \
        const float Eg = __builtin_amdgcn_exp2f(acc[ACCI][2][r_]);  /* e^{2g}*/    \
        const float Eo = __builtin_amdgcn_exp2f(acc[ACCI][3][r_]);  /* e^-o  */    \
        const float t1  = (1.0f + Ei) * (1.0f + Eg);                               \
        const float ef1 = 1.0f + Ef;                                               \
        const float t3  = (Eg - 1.0f) * ef1;                                       \
        const float num = fmaf(cst[(MTI)*4 + r_], t1, t3);                         \
        const float cn  = num * __builtin_amdgcn_rcpf(t1 * ef1);                   \
        cst[(MTI)*4 + r_] = cn;                                                    \
        const float Ec = __builtin_amdgcn_exp2f(2.0f * LOG2E * cn);                \
        const float hn = (Ec - 1.0f) *                                             \
            __builtin_amdgcn_rcpf((1.0f + Eo) * (1.0f + Ec));                      \
        (WB_)[(MTI)*16*ASTR + r_*ASTR] = f2bf_fast(hn);                            \
    }                                                                              \
} while (0)

// NOTE: __launch_bounds__ 2nd arg is CUDA-semantics min BLOCKS per CU.
// (512,2) forced 16 waves/CU -> 128-VGPR cap (R6 spilled at exactly 128).
// (512,1) -> 8 waves/CU min -> 256-reg cap; LDS (105KB) already limits us
// to 1 WG/CU, so nothing is lost and MT=160's ~140+ regs now fit.
__global__ __launch_bounds__(THREADS, 1)
void wahead_kernel(const float* __restrict__ z,   const float* __restrict__ anchors,
                   const float* __restrict__ W1,  const float* __restrict__ b1,
                   const float* __restrict__ W2,  const float* __restrict__ b2,
                   const float* __restrict__ Wih, const float* __restrict__ Whh,
                   const float* __restrict__ bih, const float* __restrict__ bhh,
                   const float* __restrict__ Wp,  const float* __restrict__ bp,
                   const float* __restrict__ Wr,  const float* __restrict__ br,
                   float* __restrict__ out)
{
    __shared__ unsigned short sA[2 * MT * ASTR];   // ping-pong [emb|h|0] bf16, 105 KB
    __shared__ float sW1[32], sb1[16], sW2[16 * 17], sb2[16], sWp[128], sWr[384];

    const int tid  = threadIdx.x;
    const int wv   = tid >> 6;       // wave 0..7: owns l-cols wv*16..wv*16+15 of each gate
    const int lane = tid & 63;
    const int quad = lane >> 4;
    const int cc   = lane & 15;
    const int lcol = wv * 16 + cc;

    // ---- stage small constant weights into LDS ----
    if (tid < 32)  sW1[tid] = W1[tid];
    if (tid < 16)  { sb1[tid] = b1[tid]; sb2[tid] = b2[tid]; }
    if (tid < 256) sW2[(tid >> 4) * 17 + (tid & 15)] = W2[tid];   // sW2[col*17+hh]
    if (tid < 128) sWp[tid] = Wp[tid];
    if (tid < 384) sWr[tid] = Wr[tid];

    // ---- zero-pad cols (144..159) of ALL rows, both buffers, ONCE ----
    // 2 bufs x 160 rows x 8 u32-pairs = 2560 pairs; 5 x 512 threads = exact.
    // (R6/R7 BUG: c<3 covered only 1536 pairs; buf1 rows 32..159 kept LDS
    // garbage -> NaN when residual bits decoded as bf16 NaN/Inf, since
    // NaN*0 != 0 in the kt=4 MFMA against the zeroed B pad.)
    {
        #pragma unroll
        for (int c = 0; c < 5; ++c) {
            const int idx  = c * 512 + tid;          // 0..2559, exact coverage
            const int bufr = idx >> 3;               // buf*MT + row (0..319)
            const int cp   = idx & 7;                // u32 pair within pad
            *reinterpret_cast<unsigned*>(&sA[bufr * ASTR + 144 + cp * 2]) = 0u;
        }
    }

    // ---- stacked-B fragments [W_ih(16)|W_hh(128)|0(16)] with FOLDED gate scales ----
    // gates i,f,o scaled by -log2e; gate g scaled by +2*log2e, so exp2() applies
    // directly to the MFMA accumulators.  B layout (16x16x32): n=lane&15, k=quad*8+j
    bf16x8 Bf[4][5];
    float  biasv[4];
    #pragma unroll
    for (int t = 0; t < 4; ++t) {                      // gate i,f,g,o
        const float sc = (t == 2) ? (2.0f * LOG2E) : (-LOG2E);
        const int n = t * 128 + wv * 16 + cc;          // gate output col in [0,512)
        biasv[t] = sc * (bih[n] + bhh[n]);
        #pragma unroll
        for (int kt = 0; kt < 5; ++kt) {
            const int k0 = kt * 32 + quad * 8;
            float v[8];
            if (k0 < 16) {                             // W_ih region
                const float4 p0 = *reinterpret_cast<const float4*>(Wih + n * 16 + k0);
                const float4 p1 = *reinterpret_cast<const float4*>(Wih + n * 16 + k0 + 4);
                v[0]=p0.x; v[1]=p0.y; v[2]=p0.z; v[3]=p0.w;
                v[4]=p1.x; v[5]=p1.y; v[6]=p1.z; v[7]=p1.w;
            } else if (k0 < 144) {                     // W_hh region
                const float4 p0 = *reinterpret_cast<const float4*>(Whh + n * 128 + (k0 - 16));
                const float4 p1 = *reinterpret_cast<const float4*>(Whh + n * 128 + (k0 - 16) + 4);
                v[0]=p0.x; v[1]=p0.y; v[2]=p0.z; v[3]=p0.w;
                v[4]=p1.x; v[5]=p1.y; v[6]=p1.z; v[7]=p1.w;
            } else {                                   // zero pad k in [144,160)
                #pragma unroll
                for (int j = 0; j < 8; ++j) v[j] = 0.0f;
            }
            union { bf16x8 bv; unsigned short us[8]; } pk;
            #pragma unroll
            for (int j = 0; j < 8; ++j) pk.us[j] = f2bf(sc * v[j]);
            Bf[t][kt] = pk.bv;
        }
    }

    const float bpv = bp[0];
    const float br0 = br[0], br1 = br[1], br2 = br[2];

    __syncthreads();   // consts + pad staged

    const int erow = tid >> 2;   // 0..127 (4 threads per row)
    const int esub = tid & 3;    // 0..3

    // ---- per-thread LDS base pointers (per buffer): step addressing is
    //      base + compile-time immediate ----
    const unsigned short* rbB[2];   // A-frag read base: row cc, k-offset quad*8
    unsigned short*       wbB[2];   // h write base: row quad*4, col 16+lcol
    rbB[0] = &sA[0 * MT * ASTR + cc * ASTR + quad * 8];
    rbB[1] = &sA[1 * MT * ASTR + cc * ASTR + quad * 8];
    wbB[0] = &sA[0 * MT * ASTR + (quad * 4) * ASTR + 16 + lcol];
    wbB[1] = &sA[1 * MT * ASTR + (quad * 4) * ASTR + 16 + lcol];

    #pragma unroll 1
    for (int ti = 0; ti < TPW; ++ti) {
        const int tile = blockIdx.x * TPW + ti;
        const int r0g  = tile * MT;

        // -------- staging: emb MLP (4 cols/thread) + initial h = z --------
        // two passes: rows 0..127 (all threads), rows 128..159 (tid<128)
        #pragma unroll 1
        for (int rr = erow; rr < MT; rr += 128) {
            const int gr = r0g + rr;
            const float2 an = *reinterpret_cast<const float2*>(anchors + gr * 2);
            const int e0 = esub * 4;
            float a0 = sb2[e0], a1 = sb2[e0 + 1], a2 = sb2[e0 + 2], a3 = sb2[e0 + 3];
            #pragma unroll
            for (int hh = 0; hh < 16; ++hh) {
                float pre = fmaf(sW1[hh * 2], an.x, fmaf(sW1[hh * 2 + 1], an.y, sb1[hh]));
                pre = fmaxf(pre, 0.0f);
                a0 = fmaf(pre, sW2[e0 * 17 + hh], a0);
                a1 = fmaf(pre, sW2[(e0 + 1) * 17 + hh], a1);
                a2 = fmaf(pre, sW2[(e0 + 2) * 17 + hh], a2);
                a3 = fmaf(pre, sW2[(e0 + 3) * 17 + hh], a3);
            }
            const unsigned ep0 = pk2bf(a0, a1), ep1 = pk2bf(a2, a3);
            #pragma unroll
            for (int bufi = 0; bufi < 2; ++bufi) {
                unsigned short* row = &sA[bufi * MT * ASTR + rr * ASTR];
                *reinterpret_cast<unsigned*>(&row[e0])     = ep0;
                *reinterpret_cast<unsigned*>(&row[e0 + 2]) = ep1;
            }
            // initial h = z[b] (bf16) into buffer 0, cols 16..143: 32 elems/thread
            const unsigned b_idx = (unsigned)gr / 5u;
            const float* zb = z + (size_t)b_idx * 128 + esub * 32;
            unsigned short* hrow = &sA[rr * ASTR + 16 + esub * 32];
            #pragma unroll
            for (int c = 0; c < 2; ++c) {
                const float4 q0 = *reinterpret_cast<const float4*>(zb + c * 16);
                const float4 q1 = *reinterpret_cast<const float4*>(zb + c * 16 + 4);
                const float4 q2 = *reinterpret_cast<const float4*>(zb + c * 16 + 8);
                const float4 q3 = *reinterpret_cast<const float4*>(zb + c * 16 + 12);
                union { u16x8 v; unsigned u32[4]; } w0, w1;
                w0.u32[0] = pk2bf(q0.x, q0.y); w0.u32[1] = pk2bf(q0.z, q0.w);
                w0.u32[2] = pk2bf(q1.x, q1.y); w0.u32[3] = pk2bf(q1.z, q1.w);
                w1.u32[0] = pk2bf(q2.x, q2.y); w1.u32[1] = pk2bf(q2.z, q2.w);
                w1.u32[2] = pk2bf(q3.x, q3.y); w1.u32[3] = pk2bf(q3.z, q3.w);
                *reinterpret_cast<u16x8*>(hrow + c * 16)     = w0.v;
                *reinterpret_cast<u16x8*>(hrow + c * 16 + 8) = w1.v;
            }
        }

        float cst[4 * NMT];
        #pragma unroll
        for (int e = 0; e < 4 * NMT; ++e) cst[e] = 0.0f;

        #pragma unroll
        for (int s = 0; s < HN; ++s) {
            const int cur = s & 1;          // compile-time after unroll
            const int nxt = cur ^ 1;
            __syncthreads();   // staging / previous-step h writes visible

            const unsigned short* rb = rbB[cur];
            unsigned short*       wb = wbB[nxt];

            // ---- 10 m-tiles: MFMA(mt) with af ping-pong prefetch; PW(mt-1)
            //      issued in MFMA(mt)'s window via acc bank ping-pong ----
            f32x4 acc[2][4];
            bf16x8 af[2][5];
            #pragma unroll
            for (int kt = 0; kt < 5; ++kt)
                af[0][kt] = *reinterpret_cast<const bf16x8*>(rb + kt * 32);

            #pragma unroll
            for (int mt = 0; mt < NMT; ++mt) {
                const int pb = mt & 1;
                #pragma unroll
                for (int t = 0; t < 4; ++t)
                    acc[pb][t] = splat4(biasv[t]);
                if (mt < NMT - 1) {
                    #pragma unroll
                    for (int kt = 0; kt < 5; ++kt)
                        af[pb ^ 1][kt] = *reinterpret_cast<const bf16x8*>(
                            rb + (mt + 1) * 16 * ASTR + kt * 32);
                }
                #pragma unroll
                for (int kt = 0; kt < 5; ++kt)
                    #pragma unroll
                    for (int t = 0; t < 4; ++t)
                        acc[pb][t] = __builtin_amdgcn_mfma_f32_16x16x32_bf16(
                            af[pb][kt], Bf[t][kt], acc[pb][t], 0, 0, 0);
                // pointwise of previous m-tile (independent of this mt's MFMAs)
                if      (mt == 1) PW_MT(0, 0, wb);
                else if (mt == 2) PW_MT(1, 1, wb);
                else if (mt == 3) PW_MT(0, 2, wb);
                else if (mt == 4) PW_MT(1, 3, wb);
                else if (mt == 5) PW_MT(0, 4, wb);
                else if (mt == 6) PW_MT(1, 5, wb);
                else if (mt == 7) PW_MT(0, 6, wb);
                else if (mt == 8) PW_MT(1, 7, wb);
                else if (mt == 9) PW_MT(0, 8, wb);
            }
            PW_MT(1, 9, wb);
        }

        __syncthreads();   // final h (buffer 1) complete

        // -------- epilogue: heads; 4 threads/row, 32 l each; two passes --------
        #pragma unroll 1
        for (int rr = erow; rr < MT; rr += 128) {
            const int j = esub;          // 0..3
            const unsigned short* hrow = &sA[1 * MT * ASTR + rr * ASTR + 16 + j * 32];
            float p = 0.f, q0 = 0.f, q1 = 0.f, q2 = 0.f;
            #pragma unroll
            for (int c = 0; c < 4; ++c) {
                const u16x8 hv8 = *reinterpret_cast<const u16x8*>(hrow + c * 8);
                #pragma unroll
                for (int u = 0; u < 8; ++u) {
                    const int l = j * 32 + c * 8 + u;
                    const float hv = bf2f(hv8[u]);
                    p  = fmaf(hv, sWp[l], p);
                    q0 = fmaf(hv, sWr[l], q0);
                    q1 = fmaf(hv, sWr[128 + l], q1);
                    q2 = fmaf(hv, sWr[256 + l], q2);
                }
            }
            #pragma unroll
            for (int m = 1; m < 4; m <<= 1) {
                p  += __shfl_xor(p,  m, 64);
                q0 += __shfl_xor(q0, m, 64);
                q1 += __shfl_xor(q1, m, 64);
                q2 += __shfl_xor(q2, m, 64);
            }
            if (j == 0) {
                const int gr = r0g + rr;
                const float prog  = p + bpv;
                const float rr0 = q0 + br0, rr1 = q1 + br1, rr2 = q2 + br2;
                const float rmean = (rr0 + rr1 + rr2) * (1.0f / 3.0f);
                const float s0 = sigm(rr0), s1 = sigm(rr1), s2 = sigm(rr2);
                const float sm = (s0 + s1 + s2) * (1.0f / 3.0f);
                const float d0 = s0 - sm, d1 = s1 - sm, d2 = s2 - sm;
                const float unc = (d0 * d0 + d1 * d1 + d2 * d2) * 0.5f;   // ddof=1
                out[gr]          = rmean;
                out[BK + gr]     = prog;
                out[2 * BK + gr] = unc;
                out[3 * BK + gr] = rr0;
                out[4 * BK + gr] = rr1;
                out[5 * BK + gr] = rr2;
            }
        }
        // next-tile staging writes emb cols (both bufs) + buf0 h (z);
        // epilogue reads buf1 h-cols — disjoint; step-0 barrier orders the rest.
    }
}

extern "C" void kernel_launch(void* const* d_in, const int* in_sizes, int n_in,
                              void* d_out, int out_size, void* d_ws, size_t ws_size,
                              hipStream_t stream) {
    const float* z       = (const float*)d_in[0];
    const float* anchors = (const float*)d_in[1];
    const float* W1      = (const float*)d_in[2];
    const float* b1      = (const float*)d_in[3];
    const float* W2      = (const float*)d_in[4];
    const float* b2      = (const float*)d_in[5];
    const float* Wih     = (const float*)d_in[6];
    const float* Whh     = (const float*)d_in[7];
    const float* bih     = (const float*)d_in[8];
    const float* bhh     = (const float*)d_in[9];
    const float* Wp      = (const float*)d_in[10];
    const float* bp      = (const float*)d_in[11];
    const float* Wr      = (const float*)d_in[12];
    const float* br      = (const float*)d_in[13];

    hipLaunchKernelGGL(wahead_kernel, dim3(WGS), dim3(THREADS), 0, stream,
                       z, anchors, W1, b1, W2, b2, Wih, Whh, bih, bhh,
                       Wp, bp, Wr, br, (float*)d_out);
}

// Round 9
// 196.566 us; speedup vs baseline: 1.0325x; 1.0303x over previous
//
#include <hip/hip_runtime.h>

// Problem constants
#define BN 32768
#define KN 5
#define LN 128
#define HN 3
#define ROWS (BN*KN)        // 163840
#define BK ROWS
#define MT 128              // rows per tile (R5-verified sweet spot)
#define TILES (ROWS/MT)     // 1280
#define WGS 256             // one WG per CU, single round
#define TPW (TILES/WGS)     // 5 tiles per workgroup
#define THREADS 512         // 8 waves
#define ASTR 168            // A row stride bf16: [emb16|h128|zero16] + 8 pad
#define LOG2E 1.44269504089f

using bf16x8 = __attribute__((ext_vector_type(8))) __bf16;
using bf16x2 = __attribute__((ext_vector_type(2))) __bf16;
using f32x4  = __attribute__((ext_vector_type(4))) float;
using u16x8  = __attribute__((ext_vector_type(8))) unsigned short;

__device__ inline unsigned short f2bf(float x) {
    union { float f; unsigned u; } v; v.f = x;
    unsigned r = v.u + 0x7FFFu + ((v.u >> 16) & 1u);   // RNE
    return (unsigned short)(r >> 16);
}
#if __has_builtin(__builtin_amdgcn_cvt_pk_bf16_f32)
__device__ inline unsigned short f2bf_fast(float x) {
    union { bf16x2 v; unsigned short us[2]; } u;
    u.v = __builtin_amdgcn_cvt_pk_bf16_f32(x, x);
    return u.us[0];
}
__device__ inline unsigned pk2bf(float lo, float hi) {   // D.lo=bf16(S0), D.hi=bf16(S1)
    union { bf16x2 v; unsigned u; } q;
    q.v = __builtin_amdgcn_cvt_pk_bf16_f32(lo, hi);
    return q.u;
}
#else
__device__ inline unsigned short f2bf_fast(float x) { return f2bf(x); }
__device__ inline unsigned pk2bf(float lo, float hi) {
    return (unsigned)f2bf(lo) | ((unsigned)f2bf(hi) << 16);
}
#endif
__device__ inline float bf2f(unsigned short b) {
    union { unsigned u; float f; } v; v.u = ((unsigned)b) << 16; return v.f;
}
__device__ inline float sigm(float x) {
    return __builtin_amdgcn_rcpf(1.0f + __builtin_amdgcn_exp2f(-LOG2E * x));
}
__device__ inline f32x4 splat4(float x) { f32x4 r; r[0]=x; r[1]=x; r[2]=x; r[3]=x; return r; }

// Pointwise LSTM nonlinearity for one m-tile (4 acc rows), acc bank ACCI,
// logical m-tile MTI (0..7). WB_ = per-thread write base into next h buffer.
#define PW_MT(ACCI, MTI, WB_) do {                                                 \
    _Pragma("unroll")                                                              \
    for (int r_ = 0; r_ < 4; ++r_) {                                               \
        const float Ei = __builtin_amdgcn_exp2f(acc[ACCI][0][r_]);  /* e^-i  */    \
        const float Ef = __builtin_amdgcn_exp2f(acc[ACCI][1][r_]);  /* e^-f  */    \
        const float Eg = __builtin_amdgcn_exp2f(acc[ACCI][2][r_]);  /* e^{2g}*/    \
        const float Eo = __builtin_amdgcn_exp2f(acc[ACCI][3][r_]);  /* e^-o  */    \
        const float t1  = (1.0f + Ei) * (1.0f + Eg);                               \
        const float ef1 = 1.0f + Ef;                                               \
        const float t3  = (Eg - 1.0f) * ef1;                                       \
        const float num = fmaf(cst[(MTI)*4 + r_], t1, t3);                         \
        const float cn  = num * __builtin_amdgcn_rcpf(t1 * ef1);                   \
        cst[(MTI)*4 + r_] = cn;                                                    \
        const float Ec = __builtin_amdgcn_exp2f(2.0f * LOG2E * cn);                \
        const float hn = (Ec - 1.0f) *                                             \
            __builtin_amdgcn_rcpf((1.0f + Eo) * (1.0f + Ec));                      \
        (WB_)[(MTI)*16*ASTR + r_*ASTR] = f2bf_fast(hn);                            \
    }                                                                              \
} while (0)

__global__ __launch_bounds__(THREADS, 2)
void wahead_kernel(const float* __restrict__ z,   const float* __restrict__ anchors,
                   const float* __restrict__ W1,  const float* __restrict__ b1,
                   const float* __restrict__ W2,  const float* __restrict__ b2,
                   const float* __restrict__ Wih, const float* __restrict__ Whh,
                   const float* __restrict__ bih, const float* __restrict__ bhh,
                   const float* __restrict__ Wp,  const float* __restrict__ bp,
                   const float* __restrict__ Wr,  const float* __restrict__ br,
                   float* __restrict__ out)
{
    __shared__ unsigned short sA[2 * MT * ASTR];   // ping-pong [emb|h|0] bf16, 86 KB
    __shared__ float sW1[32], sb1[16], sW2[16 * 17], sb2[16], sWp[128], sWr[384];

    const int tid  = threadIdx.x;
    const int wv   = tid >> 6;       // wave 0..7: owns l-cols wv*16..wv*16+15 of each gate
    const int lane = tid & 63;
    const int quad = lane >> 4;
    const int cc   = lane & 15;
    const int lcol = wv * 16 + cc;

    // ---- stage small constant weights into LDS ----
    if (tid < 32)  sW1[tid] = W1[tid];
    if (tid < 16)  { sb1[tid] = b1[tid]; sb2[tid] = b2[tid]; }
    if (tid < 256) sW2[(tid >> 4) * 17 + (tid & 15)] = W2[tid];   // sW2[col*17+hh]
    if (tid < 128) sWp[tid] = Wp[tid];
    if (tid < 384) sWr[tid] = Wr[tid];

    // ---- stacked-B fragments [W_ih(16)|W_hh(128)|0(16)] with FOLDED gate scales ----
    // gates i,f,o scaled by -log2e; gate g scaled by +2*log2e, so exp2() applies
    // directly to the MFMA accumulators.  B layout (16x16x32): n=lane&15, k=quad*8+j
    bf16x8 Bf[4][5];
    float  biasv[4];
    #pragma unroll
    for (int t = 0; t < 4; ++t) {                      // gate i,f,g,o
        const float sc = (t == 2) ? (2.0f * LOG2E) : (-LOG2E);
        const int n = t * 128 + wv * 16 + cc;          // gate output col in [0,512)
        biasv[t] = sc * (bih[n] + bhh[n]);
        #pragma unroll
        for (int kt = 0; kt < 5; ++kt) {
            const int k0 = kt * 32 + quad * 8;
            float v[8];
            if (k0 < 16) {                             // W_ih region
                const float4 p0 = *reinterpret_cast<const float4*>(Wih + n * 16 + k0);
                const float4 p1 = *reinterpret_cast<const float4*>(Wih + n * 16 + k0 + 4);
                v[0]=p0.x; v[1]=p0.y; v[2]=p0.z; v[3]=p0.w;
                v[4]=p1.x; v[5]=p1.y; v[6]=p1.z; v[7]=p1.w;
            } else if (k0 < 144) {                     // W_hh region
                const float4 p0 = *reinterpret_cast<const float4*>(Whh + n * 128 + (k0 - 16));
                const float4 p1 = *reinterpret_cast<const float4*>(Whh + n * 128 + (k0 - 16) + 4);
                v[0]=p0.x; v[1]=p0.y; v[2]=p0.z; v[3]=p0.w;
                v[4]=p1.x; v[5]=p1.y; v[6]=p1.z; v[7]=p1.w;
            } else {                                   // zero pad k in [144,160)
                #pragma unroll
                for (int j = 0; j < 8; ++j) v[j] = 0.0f;
            }
            union { bf16x8 bv; unsigned short us[8]; } pk;
            #pragma unroll
            for (int j = 0; j < 8; ++j) pk.us[j] = f2bf(sc * v[j]);
            Bf[t][kt] = pk.bv;
        }
    }

    const float bpv = bp[0];
    const float br0 = br[0], br1 = br[1], br2 = br[2];

    __syncthreads();   // consts staged

    const int erow = tid >> 2;   // 0..127 (4 threads per row)
    const int esub = tid & 3;    // 0..3

    // ---- per-thread LDS base pointers (per buffer): step addressing is
    //      base + compile-time immediate ----
    const unsigned short* rbB[2];   // A-frag read base: row cc, k-offset quad*8
    unsigned short*       wbB[2];   // h write base: row quad*4, col 16+lcol
    rbB[0] = &sA[0 * MT * ASTR + cc * ASTR + quad * 8];
    rbB[1] = &sA[1 * MT * ASTR + cc * ASTR + quad * 8];
    wbB[0] = &sA[0 * MT * ASTR + (quad * 4) * ASTR + 16 + lcol];
    wbB[1] = &sA[1 * MT * ASTR + (quad * 4) * ASTR + 16 + lcol];

    #pragma unroll 1
    for (int ti = 0; ti < TPW; ++ti) {
        const int tile = blockIdx.x * TPW + ti;
        const int r0g  = tile * MT;

        // -------- staging: emb MLP (4 cols/thread) + zero-pad + z --------
        {
            const int gr = r0g + erow;
            const float2 an = *reinterpret_cast<const float2*>(anchors + gr * 2);
            const int e0 = esub * 4;
            float a0 = sb2[e0], a1 = sb2[e0 + 1], a2 = sb2[e0 + 2], a3 = sb2[e0 + 3];
            #pragma unroll
            for (int hh = 0; hh < 16; ++hh) {
                float pre = fmaf(sW1[hh * 2], an.x, fmaf(sW1[hh * 2 + 1], an.y, sb1[hh]));
                pre = fmaxf(pre, 0.0f);
                a0 = fmaf(pre, sW2[e0 * 17 + hh], a0);
                a1 = fmaf(pre, sW2[(e0 + 1) * 17 + hh], a1);
                a2 = fmaf(pre, sW2[(e0 + 2) * 17 + hh], a2);
                a3 = fmaf(pre, sW2[(e0 + 3) * 17 + hh], a3);
            }
            const unsigned ep0 = pk2bf(a0, a1), ep1 = pk2bf(a2, a3);
            #pragma unroll
            for (int bufi = 0; bufi < 2; ++bufi) {
                unsigned short* row = &sA[bufi * MT * ASTR + erow * ASTR];
                *reinterpret_cast<unsigned*>(&row[e0])       = ep0;
                *reinterpret_cast<unsigned*>(&row[e0 + 2])   = ep1;
                *reinterpret_cast<unsigned*>(&row[144 + e0]) = 0u;
                *reinterpret_cast<unsigned*>(&row[144 + e0 + 2]) = 0u;
            }
            // initial h = z[b] (bf16) into buffer 0, cols 16..143: 32 elems/thread
            const unsigned b_idx = (unsigned)gr / 5u;
            const float* zb = z + (size_t)b_idx * 128 + esub * 32;
            unsigned short* hrow = &sA[erow * ASTR + 16 + esub * 32];
            #pragma unroll
            for (int c = 0; c < 2; ++c) {
                const float4 q0 = *reinterpret_cast<const float4*>(zb + c * 16);
                const float4 q1 = *reinterpret_cast<const float4*>(zb + c * 16 + 4);
                const float4 q2 = *reinterpret_cast<const float4*>(zb + c * 16 + 8);
                const float4 q3 = *reinterpret_cast<const float4*>(zb + c * 16 + 12);
                union { u16x8 v; unsigned u32[4]; } w0, w1;
                w0.u32[0] = pk2bf(q0.x, q0.y); w0.u32[1] = pk2bf(q0.z, q0.w);
                w0.u32[2] = pk2bf(q1.x, q1.y); w0.u32[3] = pk2bf(q1.z, q1.w);
                w1.u32[0] = pk2bf(q2.x, q2.y); w1.u32[1] = pk2bf(q2.z, q2.w);
                w1.u32[2] = pk2bf(q3.x, q3.y); w1.u32[3] = pk2bf(q3.z, q3.w);
                *reinterpret_cast<u16x8*>(hrow + c * 16)     = w0.v;
                *reinterpret_cast<u16x8*>(hrow + c * 16 + 8) = w1.v;
            }
        }

        float cst[32];
        #pragma unroll
        for (int e = 0; e < 32; ++e) cst[e] = 0.0f;

        #pragma unroll
        for (int s = 0; s < HN; ++s) {
            const int cur = s & 1;          // compile-time after unroll
            const int nxt = cur ^ 1;
            __syncthreads();   // staging / previous-step h writes visible

            const unsigned short* rb = rbB[cur];
            unsigned short*       wb = wbB[nxt];

            // ---- 8 m-tiles: MFMA(mt) with af ping-pong prefetch; PW(mt-1)
            //      issued in MFMA(mt)'s window via acc bank ping-pong ----
            f32x4 acc[2][4];
            bf16x8 af[2][5];
            #pragma unroll
            for (int kt = 0; kt < 5; ++kt)
                af[0][kt] = *reinterpret_cast<const bf16x8*>(rb + kt * 32);

            #pragma unroll
            for (int mt = 0; mt < 8; ++mt) {
                const int pb = mt & 1;
                #pragma unroll
                for (int t = 0; t < 4; ++t)
                    acc[pb][t] = splat4(biasv[t]);
                if (mt < 7) {
                    #pragma unroll
                    for (int kt = 0; kt < 5; ++kt)
                        af[pb ^ 1][kt] = *reinterpret_cast<const bf16x8*>(
                            rb + (mt + 1) * 16 * ASTR + kt * 32);
                }
                #pragma unroll
                for (int kt = 0; kt < 5; ++kt)
                    #pragma unroll
                    for (int t = 0; t < 4; ++t)
                        acc[pb][t] = __builtin_amdgcn_mfma_f32_16x16x32_bf16(
                            af[pb][kt], Bf[t][kt], acc[pb][t], 0, 0, 0);
                // pointwise of previous m-tile (independent of this mt's MFMAs)
                if (mt == 1) PW_MT(0, 0, wb);
                else if (mt == 2) PW_MT(1, 1, wb);
                else if (mt == 3) PW_MT(0, 2, wb);
                else if (mt == 4) PW_MT(1, 3, wb);
                else if (mt == 5) PW_MT(0, 4, wb);
                else if (mt == 6) PW_MT(1, 5, wb);
                else if (mt == 7) PW_MT(0, 6, wb);
            }
            PW_MT(1, 7, wb);
        }

        __syncthreads();   // final h (buffer 1) complete

        // -------- epilogue: heads; 4 threads/row, 32 l each --------
        {
            const int row = tid >> 2;    // 0..127
            const int j   = tid & 3;     // 0..3
            const unsigned short* hrow = &sA[1 * MT * ASTR + row * ASTR + 16 + j * 32];
            float p = 0.f, q0 = 0.f, q1 = 0.f, q2 = 0.f;
            #pragma unroll
            for (int c = 0; c < 4; ++c) {
                const u16x8 hv8 = *reinterpret_cast<const u16x8*>(hrow + c * 8);
                #pragma unroll
                for (int u = 0; u < 8; ++u) {
                    const int l = j * 32 + c * 8 + u;
                    const float hv = bf2f(hv8[u]);
                    p  = fmaf(hv, sWp[l], p);
                    q0 = fmaf(hv, sWr[l], q0);
                    q1 = fmaf(hv, sWr[128 + l], q1);
                    q2 = fmaf(hv, sWr[256 + l], q2);
                }
            }
            #pragma unroll
            for (int m = 1; m < 4; m <<= 1) {
                p  += __shfl_xor(p,  m, 64);
                q0 += __shfl_xor(q0, m, 64);
                q1 += __shfl_xor(q1, m, 64);
                q2 += __shfl_xor(q2, m, 64);
            }
            if (j == 0) {
                const int gr = r0g + row;
                const float prog  = p + bpv;
                const float rr0 = q0 + br0, rr1 = q1 + br1, rr2 = q2 + br2;
                const float rmean = (rr0 + rr1 + rr2) * (1.0f / 3.0f);
                const float s0 = sigm(rr0), s1 = sigm(rr1), s2 = sigm(rr2);
                const float sm = (s0 + s1 + s2) * (1.0f / 3.0f);
                const float d0 = s0 - sm, d1 = s1 - sm, d2 = s2 - sm;
                const float unc = (d0 * d0 + d1 * d1 + d2 * d2) * 0.5f;   // ddof=1
                out[gr]          = rmean;
                out[BK + gr]     = prog;
                out[2 * BK + gr] = unc;
                out[3 * BK + gr] = rr0;
                out[4 * BK + gr] = rr1;
                out[5 * BK + gr] = rr2;
            }
        }
        // next-tile staging writes emb cols (both bufs) + buf0 h (z);
        // epilogue reads buf1 h-cols — disjoint; step-0 barrier orders the rest.
    }
}

extern "C" void kernel_launch(void* const* d_in, const int* in_sizes, int n_in,
                              void* d_out, int out_size, void* d_ws, size_t ws_size,
                              hipStream_t stream) {
    const float* z       = (const float*)d_in[0];
    const float* anchors = (const float*)d_in[1];
    const float* W1      = (const float*)d_in[2];
    const float* b1      = (const float*)d_in[3];
    const float* W2      = (const float*)d_in[4];
    const float* b2      = (const float*)d_in[5];
    const float* Wih     = (const float*)d_in[6];
    const float* Whh     = (const float*)d_in[7];
    const float* bih     = (const float*)d_in[8];
    const float* bhh     = (const float*)d_in[9];
    const float* Wp      = (const float*)d_in[10];
    const float* bp      = (const float*)d_in[11];
    const float* Wr      = (const float*)d_in[12];
    const float* br      = (const float*)d_in[13];

    hipLaunchKernelGGL(wahead_kernel, dim3(WGS), dim3(THREADS), 0, stream,
                       z, anchors, W1, b1, W2, b2, Wih, Whh, bih, bhh,
                       Wp, bp, Wr, br, (float*)d_out);
}